// Round 7
// baseline (668.140 us; speedup 1.0000x reference)
//
#include <hip/hip_runtime.h>
#include <hip/hip_cooperative_groups.h>
#include <math.h>

namespace cg = cooperative_groups;

#define NEG 0.2f

typedef short bf16x8 __attribute__((ext_vector_type(8)));
typedef float f32x4  __attribute__((ext_vector_type(4)));

// ---------------------------------------------------------------------------
// helpers
// ---------------------------------------------------------------------------
static __device__ __forceinline__ void fma4(float4& d, float s, const float4 w) {
    d.x = fmaf(s, w.x, d.x); d.y = fmaf(s, w.y, d.y);
    d.z = fmaf(s, w.z, d.z); d.w = fmaf(s, w.w, d.w);
}
// leaky relu of (a+b): max(v, 0.2v) — valid since slope in (0,1)
static __device__ __forceinline__ float4 lrelu4(float4 a, float4 b) {
    float4 r; float v;
    v = a.x + b.x; r.x = fmaxf(v, NEG * v);
    v = a.y + b.y; r.y = fmaxf(v, NEG * v);
    v = a.z + b.z; r.z = fmaxf(v, NEG * v);
    v = a.w + b.w; r.w = fmaxf(v, NEG * v);
    return r;
}
static __device__ __forceinline__ unsigned short f2bf(float f) {   // RNE, finite
    unsigned int x = __float_as_uint(f);
    unsigned int r = (x + 0x7FFFu + ((x >> 16) & 1u)) >> 16;
    return (unsigned short)r;
}
static __device__ __forceinline__ float rlane(float v, int l) {
    return __int_as_float(__builtin_amdgcn_readlane(__float_as_int(v), l));
}

// Sum across each 16-lane DPP row (head h = lanes 16h..16h+15).
#define DPP_ADD(x, ctrl) \
    ((x) + __int_as_float(__builtin_amdgcn_update_dpp( \
        __float_as_int(x), __float_as_int(x), (ctrl), 0xF, 0xF, true)))
static __device__ __forceinline__ float rowsum16(float v) {
    v = DPP_ADD(v, 0xB1);   // quad_perm xor1
    v = DPP_ADD(v, 0x4E);   // quad_perm xor2
    v = DPP_ADD(v, 0x141);  // row_half_mirror
    v = DPP_ADD(v, 0x140);  // row_mirror
    return v;
}

// ---------------------------------------------------------------------------
// Cooperative CSR build: zero+transpose -> hist -> scan -> scatter, one
// dispatch with 3 grid syncs (replaces 4 serially-dependent tiny dispatches).
// 1024 blocks x 256 thr (4 blocks/CU, ~32 VGPR, 1KB LDS -> all resident).
// After this kernel cur_s/cur_n are INCLUSIVE prefix (bump-allocated ends).
// ---------------------------------------------------------------------------
__global__ __launch_bounds__(256) void k_csr(
    const int* __restrict__ dst_s, const int* __restrict__ src_s, int Es,
    const int* __restrict__ dst_n, const int* __restrict__ src_n, int En,
    int* __restrict__ cur_s, int* __restrict__ cur_n,
    int* __restrict__ csr_s, int* __restrict__ csr_n, int n,
    const float* __restrict__ W, unsigned short* __restrict__ Wt)
{
    cg::grid_group grid = cg::this_grid();
    const int tid = blockIdx.x * 256 + threadIdx.x;
    const int nth = gridDim.x * 256;

    // phase 0: zero counters + transpose W_aggr to bf16 [256][512]
    for (int i = tid; i < n; i += nth) { cur_s[i] = 0; cur_n[i] = 0; }
    for (int i = tid; i < 512 * 256; i += nth) {
        int k = i >> 8, c = i & 255;
        Wt[(size_t)c * 512 + k] = f2bf(W[i]);
    }
    grid.sync();

    // phase 1: degree histogram
    for (int i = tid; i < Es; i += nth) atomicAdd(&cur_s[dst_s[i]], 1);
    for (int i = tid; i < En; i += nth) atomicAdd(&cur_n[dst_n[i]], 1);
    grid.sync();

    // phase 2: in-place exclusive scan (blocks 0 and 1; others wait)
    if (blockIdx.x < 2) {
        int* p = (blockIdx.x == 0) ? cur_s : cur_n;
        __shared__ int sums[256];
        int t = threadIdx.x;
        int C = (n + 255) >> 8;
        int base = t * C;
        int s = 0;
        for (int j = 0; j < C; ++j) { int i = base + j; if (i < n) s += p[i]; }
        sums[t] = s;
        __syncthreads();
        for (int off = 1; off < 256; off <<= 1) {
            int v = (t >= off) ? sums[t - off] : 0;
            __syncthreads();
            sums[t] += v;
            __syncthreads();
        }
        int run = t ? sums[t - 1] : 0;
        for (int j = 0; j < C; ++j) {
            int i = base + j;
            if (i < n) { int v = p[i]; p[i] = run; run += v; }
        }
    }
    grid.sync();

    // phase 3: scatter (bumps cur to inclusive prefix)
    for (int i = tid; i < Es; i += nth) {
        int pos = atomicAdd(&cur_s[dst_s[i]], 1);
        csr_s[pos] = src_s[i];
    }
    for (int i = tid; i < En; i += nth) {
        int pos = atomicAdd(&cur_n[dst_n[i]], 1);
        csr_n[pos] = src_n[i];
    }
}

// ---------------------------------------------------------------------------
// GATv2, both layers fused by contiguous block ranges (block < gNs -> seen).
// One node per wave, 4 contiguous nodes per block, short-lived blocks, no LDS.
// Lanes are the row buffer: lane L loads word (L&7) of row csr[base+(L>>3)];
// one global_load_dword = 8 edge rows in flight; chunk double-buffer costs
// 1 VGPR. Row words consumed via v_readlane (immediate lane -> SGPR FMAs).
// NO online max: |attn|~0.1 bounds |score|<~10, exp cannot overflow, so
// plain p=exp(sc) accumulation == reference softmax (denominator ratio is
// shift-invariant). This removes the loop-carried max/rescale chain.
// ---------------------------------------------------------------------------
__global__ __launch_bounds__(256) void k_gat(
    const float* __restrict__ xsrc_s, const int* __restrict__ pfx_s, const int* __restrict__ csr_s,
    const float* __restrict__ Ws_s, const float* __restrict__ bs_s,
    const float* __restrict__ Wd_s, const float* __restrict__ bd_s,
    const float* __restrict__ at_s,
    const float* __restrict__ Wr_s, const float* __restrict__ br_s,
    const float* __restrict__ xsrc_n, const int* __restrict__ pfx_n, const int* __restrict__ csr_n,
    const float* __restrict__ Ws_n, const float* __restrict__ bs_n,
    const float* __restrict__ Wd_n, const float* __restrict__ bd_n,
    const float* __restrict__ at_n,
    const float* __restrict__ Wr_n, const float* __restrict__ br_n,
    const float* __restrict__ x_ag,
    unsigned short* __restrict__ xcat, int n_dst, int gNs)
{
    const bool seen = (int)blockIdx.x < gNs;
    const float* x_src = seen ? xsrc_s : xsrc_n;
    const int*   pfx   = seen ? pfx_s  : pfx_n;
    const int*   csr   = seen ? csr_s  : csr_n;
    const float* Ws    = seen ? Ws_s   : Ws_n;
    const float* bs    = seen ? bs_s   : bs_n;
    const float* Wd    = seen ? Wd_s   : Wd_n;
    const float* bd    = seen ? bd_s   : bd_n;
    const float* at    = seen ? at_s   : at_n;
    const float* Wr    = seen ? Wr_s   : Wr_n;
    const float* br    = seen ? br_s   : br_n;
    const int col = seen ? 0 : 256;
    const int blk = seen ? (int)blockIdx.x : (int)blockIdx.x - gNs;

    const int t = threadIdx.x;
    const int wave = t >> 6, lane = t & 63;
    const int d0 = lane * 4;
    const int node = blk * 4 + wave;
    if (node >= n_dst) return;

    // wave-lifetime constants (coalesced 1KB-row loads, L1/L2-resident)
    float4 ws_r[8];
#pragma unroll
    for (int k = 0; k < 8; ++k) ws_r[k] = *(const float4*)&Ws[k * 256 + d0];
    const float4 bsv = *(const float4*)&bs[d0];
    const float4 atv = *(const float4*)&at[d0];

    int end   = pfx[node];
    int start = node ? pfx[node - 1] : 0;
    int deg   = end - start;

    // fd = x_ag[node]@Wd + bd, fr = x_ag[node]@Wr + br (4 dims/lane)
    float4 fd = *(const float4*)&bd[d0];
    float4 fr = *(const float4*)&br[d0];
    {
        const float* xr = x_ag + (size_t)node * 16;
        float4 xv[4];
#pragma unroll
        for (int kq = 0; kq < 4; ++kq) xv[kq] = *(const float4*)&xr[kq * 4];
#pragma unroll
        for (int kq = 0; kq < 4; ++kq) {
#pragma unroll
            for (int kk = 0; kk < 4; ++kk) {
                int k = kq * 4 + kk;
                float xk = (kk == 0) ? xv[kq].x : (kk == 1) ? xv[kq].y
                         : (kk == 2) ? xv[kq].z : xv[kq].w;
                fma4(fd, xk, *(const float4*)&Wd[k * 256 + d0]);
                fma4(fr, xk, *(const float4*)&Wr[k * 256 + d0]);
            }
        }
    }

    float l = 0.f;
    float4 acc = make_float4(0.f, 0.f, 0.f, 0.f);

    if (deg > 0) {
        const int g  = lane >> 3;   // edge slot 0..7 within chunk
        const int w8 = lane & 7;    // word within the 8-float row

        int e0 = (g < deg) ? g : deg - 1;
        int i0 = csr[start + e0];
        float r0 = x_src[(size_t)i0 * 8 + w8];        // 8 rows in flight
        int e1 = (8 + g < deg) ? 8 + g : deg - 1;
        int i1 = csr[start + e1];

        for (int base = 0; base < deg; base += 8) {
            float r1 = x_src[(size_t)i1 * 8 + w8];
            int e2 = base + 16 + g; e2 = (e2 < deg) ? e2 : deg - 1;
            int i2 = csr[start + e2];

#pragma unroll
            for (int j = 0; j < 8; ++j) {
                if (base + j < deg) {        // wave-uniform -> scalar branch
                    float x0 = rlane(r0, j * 8 + 0);
                    float x1 = rlane(r0, j * 8 + 1);
                    float x2 = rlane(r0, j * 8 + 2);
                    float x3 = rlane(r0, j * 8 + 3);
                    float x4 = rlane(r0, j * 8 + 4);
                    float x5 = rlane(r0, j * 8 + 5);
                    float x6 = rlane(r0, j * 8 + 6);
                    float x7 = rlane(r0, j * 8 + 7);

                    float4 fs = bsv;
                    fma4(fs, x0, ws_r[0]);
                    fma4(fs, x1, ws_r[1]);
                    fma4(fs, x2, ws_r[2]);
                    fma4(fs, x3, ws_r[3]);
                    fma4(fs, x4, ws_r[4]);
                    fma4(fs, x5, ws_r[5]);
                    fma4(fs, x6, ws_r[6]);
                    fma4(fs, x7, ws_r[7]);

                    float4 tt = lrelu4(fs, fd);
                    float sc = tt.x * atv.x;
                    sc = fmaf(tt.y, atv.y, sc);
                    sc = fmaf(tt.z, atv.z, sc);
                    sc = fmaf(tt.w, atv.w, sc);
                    sc = rowsum16(sc);

                    float p = __expf(sc);   // no max shift: |sc| bounded
                    l += p;
                    acc.x = fmaf(p, fs.x, acc.x);
                    acc.y = fmaf(p, fs.y, acc.y);
                    acc.z = fmaf(p, fs.z, acc.z);
                    acc.w = fmaf(p, fs.w, acc.w);
                }
            }
            r0 = r1; i1 = i2;
        }
    }

    float inv = (l > 0.f) ? 1.f / l : 0.f;   // zero in-degree -> rst = 0
    ushort4 o;
    o.x = f2bf(fmaxf(fmaf(acc.x, inv, fr.x), 0.f));
    o.y = f2bf(fmaxf(fmaf(acc.y, inv, fr.y), 0.f));
    o.z = f2bf(fmaxf(fmaf(acc.z, inv, fr.z), 0.f));
    o.w = f2bf(fmaxf(fmaf(acc.w, inv, fr.w), 0.f));
    *(ushort4*)&xcat[(size_t)node * 512 + col + d0] = o;
}

// ---------------------------------------------------------------------------
// out = relu(X[M,512]bf16 @ W[512,256]bf16 + b) via mfma_f32_16x16x32_bf16.
// Block = 4 waves: rows rbase..rbase+15, wave w covers cols 64w..64w+63.
// A/B frags straight from L2 (no LDS). D: col n=lane&15, row m=q*4+reg.
// ---------------------------------------------------------------------------
__global__ __launch_bounds__(256) void k_mlp(
    const unsigned short* __restrict__ X, const unsigned short* __restrict__ Wt,
    const float* __restrict__ b, float* __restrict__ out, int M)
{
    const int t = threadIdx.x;
    const int wave = t >> 6, lane = t & 63;
    const int m16 = lane & 15, q = lane >> 4;
    const int rbase = blockIdx.x * 16;
    const int nbase = wave * 64;

    int rowa = rbase + m16; if (rowa >= M) rowa = M - 1;
    const unsigned short* xp = X + (size_t)rowa * 512 + q * 8;
    const unsigned short* w0 = Wt + (size_t)(nbase + m16) * 512 + q * 8;
    const unsigned short* w1 = w0 + 16 * 512;
    const unsigned short* w2 = w0 + 32 * 512;
    const unsigned short* w3 = w0 + 48 * 512;

    f32x4 ac0 = {0.f, 0.f, 0.f, 0.f}, ac1 = ac0, ac2 = ac0, ac3 = ac0;

#pragma unroll
    for (int k0 = 0; k0 < 512; k0 += 32) {
        bf16x8 a  = *(const bf16x8*)(xp + k0);
        bf16x8 b0 = *(const bf16x8*)(w0 + k0);
        bf16x8 b1 = *(const bf16x8*)(w1 + k0);
        bf16x8 b2 = *(const bf16x8*)(w2 + k0);
        bf16x8 b3 = *(const bf16x8*)(w3 + k0);
        ac0 = __builtin_amdgcn_mfma_f32_16x16x32_bf16(a, b0, ac0, 0, 0, 0);
        ac1 = __builtin_amdgcn_mfma_f32_16x16x32_bf16(a, b1, ac1, 0, 0, 0);
        ac2 = __builtin_amdgcn_mfma_f32_16x16x32_bf16(a, b2, ac2, 0, 0, 0);
        ac3 = __builtin_amdgcn_mfma_f32_16x16x32_bf16(a, b3, ac3, 0, 0, 0);
    }

#define EPI(AC, J) { \
        int coln = nbase + (J) * 16 + m16; \
        float bias = b[coln]; \
        _Pragma("unroll") \
        for (int r = 0; r < 4; ++r) { \
            int orow = rbase + q * 4 + r; \
            if (orow < M) \
                out[(size_t)orow * 256 + coln] = fmaxf(AC[r] + bias, 0.f); \
        } }
    EPI(ac0, 0) EPI(ac1, 1) EPI(ac2, 2) EPI(ac3, 3)
#undef EPI
}

// ---------------------------------------------------------------------------
extern "C" void kernel_launch(void* const* d_in, const int* in_sizes, int n_in,
                              void* d_out, int out_size, void* d_ws, size_t ws_size,
                              hipStream_t stream) {
    const float* x_gt   = (const float*)d_in[0];
    const float* x_ubs  = (const float*)d_in[1];
    const float* x_ag   = (const float*)d_in[2];
    const int* seen_src = (const int*)d_in[3];
    const int* seen_dst = (const int*)d_in[4];
    const int* near_src = (const int*)d_in[5];
    const int* near_dst = (const int*)d_in[6];
    const float* Ws_s = (const float*)d_in[7];  const float* bs_s = (const float*)d_in[8];
    const float* Wd_s = (const float*)d_in[9];  const float* bd_s = (const float*)d_in[10];
    const float* at_s = (const float*)d_in[11];
    const float* Wr_s = (const float*)d_in[12]; const float* br_s = (const float*)d_in[13];
    const float* Ws_n = (const float*)d_in[14]; const float* bs_n = (const float*)d_in[15];
    const float* Wd_n = (const float*)d_in[16]; const float* bd_n = (const float*)d_in[17];
    const float* at_n = (const float*)d_in[18];
    const float* Wr_n = (const float*)d_in[19]; const float* br_n = (const float*)d_in[20];
    const float* W_a  = (const float*)d_in[21]; const float* b_a  = (const float*)d_in[22];

    const int n_ag = in_sizes[2] / 16;
    const int E_s  = in_sizes[3];
    const int E_n  = in_sizes[5];

    char* ws = (char*)d_ws;
    int* cur_s = (int*)ws;              ws += (size_t)n_ag * 4;
    int* cur_n = (int*)ws;              ws += (size_t)n_ag * 4;
    int* csr_s = (int*)ws;              ws += (size_t)E_s * 4;
    int* csr_n = (int*)ws;              ws += (size_t)E_n * 4;
    unsigned short* xcat = (unsigned short*)ws;  ws += (size_t)n_ag * 512 * 2;
    unsigned short* Wt   = (unsigned short*)ws;  // [256][512] bf16

    // cooperative CSR build (zero+transpose | hist | scan | scatter)
    {
        void* args[] = {
            (void*)&seen_dst, (void*)&seen_src, (void*)&E_s,
            (void*)&near_dst, (void*)&near_src, (void*)&E_n,
            (void*)&cur_s, (void*)&cur_n, (void*)&csr_s, (void*)&csr_n,
            (void*)&n_ag, (void*)&W_a, (void*)&Wt
        };
        hipLaunchCooperativeKernel((void*)k_csr, dim3(1024), dim3(256),
                                   args, 0, stream);
    }

    int gN = (n_ag + 3) / 4;
    k_gat<<<2 * gN, 256, 0, stream>>>(
        x_gt,  cur_s, csr_s, Ws_s, bs_s, Wd_s, bd_s, at_s, Wr_s, br_s,
        x_ubs, cur_n, csr_n, Ws_n, bs_n, Wd_n, bd_n, at_n, Wr_n, br_n,
        x_ag, xcat, n_ag, gN);

    k_mlp<<<(n_ag + 15) / 16, 256, 0, stream>>>(xcat, Wt, b_a, (float*)d_out, n_ag);
}

// Round 8
// 359.297 us; speedup vs baseline: 1.8596x; 1.8596x over previous
//
#include <hip/hip_runtime.h>
#include <math.h>

#define NEG 0.2f

typedef short bf16x8 __attribute__((ext_vector_type(8)));
typedef float f32x4  __attribute__((ext_vector_type(4)));

// ---------------------------------------------------------------------------
// helpers
// ---------------------------------------------------------------------------
static __device__ __forceinline__ void fma4(float4& d, float s, const float4 w) {
    d.x = fmaf(s, w.x, d.x); d.y = fmaf(s, w.y, d.y);
    d.z = fmaf(s, w.z, d.z); d.w = fmaf(s, w.w, d.w);
}
// leaky relu of (a+b): max(v, 0.2v) — valid since slope in (0,1)
static __device__ __forceinline__ float4 lrelu4(float4 a, float4 b) {
    float4 r; float v;
    v = a.x + b.x; r.x = fmaxf(v, NEG * v);
    v = a.y + b.y; r.y = fmaxf(v, NEG * v);
    v = a.z + b.z; r.z = fmaxf(v, NEG * v);
    v = a.w + b.w; r.w = fmaxf(v, NEG * v);
    return r;
}
static __device__ __forceinline__ unsigned short f2bf(float f) {   // RNE, finite
    unsigned int x = __float_as_uint(f);
    unsigned int r = (x + 0x7FFFu + ((x >> 16) & 1u)) >> 16;
    return (unsigned short)r;
}
static __device__ __forceinline__ float rlane(float v, int l) {
    return __int_as_float(__builtin_amdgcn_readlane(__float_as_int(v), l));
}

// Sum across each 16-lane DPP row (head h = lanes 16h..16h+15).
#define DPP_ADD(x, ctrl) \
    ((x) + __int_as_float(__builtin_amdgcn_update_dpp( \
        __float_as_int(x), __float_as_int(x), (ctrl), 0xF, 0xF, true)))
static __device__ __forceinline__ float rowsum16(float v) {
    v = DPP_ADD(v, 0xB1);   // quad_perm xor1
    v = DPP_ADD(v, 0x4E);   // quad_perm xor2
    v = DPP_ADD(v, 0x141);  // row_half_mirror
    v = DPP_ADD(v, 0x140);  // row_mirror
    return v;
}

// ---------------------------------------------------------------------------
// CSR build (separate dispatches; cooperative grid.sync measured ~120us per
// sync on 8 XCDs in R7 -- never again). hist fused with W transpose.
// ---------------------------------------------------------------------------
__global__ void k_hist_wt(const int* __restrict__ dst_s, int Es,
                          const int* __restrict__ dst_n, int En,
                          int* __restrict__ deg_s, int* __restrict__ deg_n,
                          const float* __restrict__ W, unsigned short* __restrict__ Wt) {
    int i = blockIdx.x * 256 + threadIdx.x;
    if (i < Es) atomicAdd(&deg_s[dst_s[i]], 1);
    int j = i - Es;
    if (j >= 0 && j < En) atomicAdd(&deg_n[dst_n[j]], 1);
    if (i < 512 * 256) {                 // W[512][256] f32 -> Wt[256][512] bf16
        int k = i >> 8, n = i & 255;
        Wt[(size_t)n * 512 + k] = f2bf(W[i]);
    }
}

__global__ __launch_bounds__(1024) void k_scan2(int* a, int na, int* b, int nb) {
    int* p = (blockIdx.x == 0) ? a : b;
    int n  = (blockIdx.x == 0) ? na : nb;
    __shared__ int sums[1024];
    int t = threadIdx.x;
    int C = (n + 1023) >> 10;
    int base = t * C;
    int s = 0;
    for (int j = 0; j < C; ++j) { int i = base + j; if (i < n) s += p[i]; }
    sums[t] = s;
    __syncthreads();
    for (int off = 1; off < 1024; off <<= 1) {
        int v = (t >= off) ? sums[t - off] : 0;
        __syncthreads();
        sums[t] += v;
        __syncthreads();
    }
    int run = (t == 0) ? 0 : sums[t - 1];
    for (int j = 0; j < C; ++j) {
        int i = base + j;
        if (i < n) { int v = p[i]; p[i] = run; run += v; }
    }
}

__global__ void k_scatter(const int* __restrict__ src_s, const int* __restrict__ dst_s, int Es,
                          const int* __restrict__ src_n, const int* __restrict__ dst_n, int En,
                          int* __restrict__ cur_s, int* __restrict__ cur_n,
                          int* __restrict__ csr_s, int* __restrict__ csr_n) {
    int i = blockIdx.x * 256 + threadIdx.x;
    if (i < Es) {
        int pos = atomicAdd(&cur_s[dst_s[i]], 1);
        csr_s[pos] = src_s[i];
    }
    int j = i - Es;
    if (j >= 0 && j < En) {
        int pos = atomicAdd(&cur_n[dst_n[j]], 1);
        csr_n[pos] = src_n[j];
    }
}

// ---------------------------------------------------------------------------
// GATv2, both layers fused by contiguous block ranges (block < gNs -> seen).
// FOUR sequential nodes per wave (16 nodes per 4-wave block): ws_r / biases /
// attn loaded once per wave, and the 32 Wd/Wr lines for fd/fr are identical
// across nodes -> L1-warm after the first node. Amortizes the ~1500-cyc
// prologue that was 40% of R6's wave lifetime.
// Edge loop: lanes are the row buffer (lane L = word L&7 of edge slot L>>3,
// one dword load = 8 rows in flight, 1-VGPR double buffer -- the no-spill
// structure from R6). No online max (|score| bounded, exp can't overflow).
// ---------------------------------------------------------------------------
__global__ __launch_bounds__(256) void k_gat(
    const float* __restrict__ xsrc_s, const int* __restrict__ pfx_s, const int* __restrict__ csr_s,
    const float* __restrict__ Ws_s, const float* __restrict__ bs_s,
    const float* __restrict__ Wd_s, const float* __restrict__ bd_s,
    const float* __restrict__ at_s,
    const float* __restrict__ Wr_s, const float* __restrict__ br_s,
    const float* __restrict__ xsrc_n, const int* __restrict__ pfx_n, const int* __restrict__ csr_n,
    const float* __restrict__ Ws_n, const float* __restrict__ bs_n,
    const float* __restrict__ Wd_n, const float* __restrict__ bd_n,
    const float* __restrict__ at_n,
    const float* __restrict__ Wr_n, const float* __restrict__ br_n,
    const float* __restrict__ x_ag,
    unsigned short* __restrict__ xcat, int n_dst, int gNs)
{
    const bool seen = (int)blockIdx.x < gNs;
    const float* x_src = seen ? xsrc_s : xsrc_n;
    const int*   pfx   = seen ? pfx_s  : pfx_n;
    const int*   csr   = seen ? csr_s  : csr_n;
    const float* Ws    = seen ? Ws_s   : Ws_n;
    const float* bs    = seen ? bs_s   : bs_n;
    const float* Wd    = seen ? Wd_s   : Wd_n;
    const float* bd    = seen ? bd_s   : bd_n;
    const float* at    = seen ? at_s   : at_n;
    const float* Wr    = seen ? Wr_s   : Wr_n;
    const float* br    = seen ? br_s   : br_n;
    const int col = seen ? 0 : 256;
    const int blk = seen ? (int)blockIdx.x : (int)blockIdx.x - gNs;

    const int t = threadIdx.x;
    const int wave = t >> 6, lane = t & 63;
    const int d0 = lane * 4;

    // wave-lifetime constants (loaded ONCE for all 4 nodes)
    float4 ws_r[8];
#pragma unroll
    for (int k = 0; k < 8; ++k) ws_r[k] = *(const float4*)&Ws[k * 256 + d0];
    const float4 bsv = *(const float4*)&bs[d0];
    const float4 atv = *(const float4*)&at[d0];
    const float4 bdv = *(const float4*)&bd[d0];
    const float4 brv = *(const float4*)&br[d0];

    for (int rep = 0; rep < 4; ++rep) {
        const int node = blk * 16 + rep * 4 + wave;
        if (node >= n_dst) break;

        int end   = pfx[node];
        int start = node ? pfx[node - 1] : 0;
        int deg   = end - start;

        // fd = x_ag[node]@Wd + bd, fr = x_ag[node]@Wr + br (4 dims/lane);
        // Wd/Wr rows are the same 32 lines every node -> L1-warm after rep 0
        float4 fd = bdv, fr = brv;
        {
            const float* xr = x_ag + (size_t)node * 16;
            float4 xv[4];
#pragma unroll
            for (int kq = 0; kq < 4; ++kq) xv[kq] = *(const float4*)&xr[kq * 4];
#pragma unroll
            for (int kq = 0; kq < 4; ++kq) {
#pragma unroll
                for (int kk = 0; kk < 4; ++kk) {
                    int k = kq * 4 + kk;
                    float xk = (kk == 0) ? xv[kq].x : (kk == 1) ? xv[kq].y
                             : (kk == 2) ? xv[kq].z : xv[kq].w;
                    fma4(fd, xk, *(const float4*)&Wd[k * 256 + d0]);
                    fma4(fr, xk, *(const float4*)&Wr[k * 256 + d0]);
                }
            }
        }

        float l = 0.f;
        float4 acc = make_float4(0.f, 0.f, 0.f, 0.f);

        if (deg > 0) {
            const int g  = lane >> 3;   // edge slot 0..7 within chunk
            const int w8 = lane & 7;    // word within the 8-float row

            int e0 = (g < deg) ? g : deg - 1;
            int i0 = csr[start + e0];
            float r0 = x_src[(size_t)i0 * 8 + w8];        // 8 rows in flight
            int e1 = (8 + g < deg) ? 8 + g : deg - 1;
            int i1 = csr[start + e1];

            for (int base = 0; base < deg; base += 8) {
                float r1 = x_src[(size_t)i1 * 8 + w8];
                int e2 = base + 16 + g; e2 = (e2 < deg) ? e2 : deg - 1;
                int i2 = csr[start + e2];

#pragma unroll
                for (int j = 0; j < 8; ++j) {
                    if (base + j < deg) {      // wave-uniform -> scalar branch
                        float x0 = rlane(r0, j * 8 + 0);
                        float x1 = rlane(r0, j * 8 + 1);
                        float x2 = rlane(r0, j * 8 + 2);
                        float x3 = rlane(r0, j * 8 + 3);
                        float x4 = rlane(r0, j * 8 + 4);
                        float x5 = rlane(r0, j * 8 + 5);
                        float x6 = rlane(r0, j * 8 + 6);
                        float x7 = rlane(r0, j * 8 + 7);

                        float4 fs = bsv;
                        fma4(fs, x0, ws_r[0]);
                        fma4(fs, x1, ws_r[1]);
                        fma4(fs, x2, ws_r[2]);
                        fma4(fs, x3, ws_r[3]);
                        fma4(fs, x4, ws_r[4]);
                        fma4(fs, x5, ws_r[5]);
                        fma4(fs, x6, ws_r[6]);
                        fma4(fs, x7, ws_r[7]);

                        float4 tt = lrelu4(fs, fd);
                        float sc = tt.x * atv.x;
                        sc = fmaf(tt.y, atv.y, sc);
                        sc = fmaf(tt.z, atv.z, sc);
                        sc = fmaf(tt.w, atv.w, sc);
                        sc = rowsum16(sc);

                        float p = __expf(sc);   // no max shift: |sc| bounded
                        l += p;
                        acc.x = fmaf(p, fs.x, acc.x);
                        acc.y = fmaf(p, fs.y, acc.y);
                        acc.z = fmaf(p, fs.z, acc.z);
                        acc.w = fmaf(p, fs.w, acc.w);
                    }
                }
                r0 = r1; i1 = i2;
            }
        }

        float inv = (l > 0.f) ? 1.f / l : 0.f;   // zero in-degree -> rst = 0
        ushort4 o;
        o.x = f2bf(fmaxf(fmaf(acc.x, inv, fr.x), 0.f));
        o.y = f2bf(fmaxf(fmaf(acc.y, inv, fr.y), 0.f));
        o.z = f2bf(fmaxf(fmaf(acc.z, inv, fr.z), 0.f));
        o.w = f2bf(fmaxf(fmaf(acc.w, inv, fr.w), 0.f));
        *(ushort4*)&xcat[(size_t)node * 512 + col + d0] = o;
    }
}

// ---------------------------------------------------------------------------
// out = relu(X[M,512]bf16 @ W[512,256]bf16 + b) via mfma_f32_16x16x32_bf16.
// Block = 4 waves: rows rbase..rbase+15, wave w covers cols 64w..64w+63.
// A/B frags straight from L2 (no LDS). D: col n=lane&15, row m=q*4+reg.
// ---------------------------------------------------------------------------
__global__ __launch_bounds__(256) void k_mlp(
    const unsigned short* __restrict__ X, const unsigned short* __restrict__ Wt,
    const float* __restrict__ b, float* __restrict__ out, int M)
{
    const int t = threadIdx.x;
    const int wave = t >> 6, lane = t & 63;
    const int m16 = lane & 15, q = lane >> 4;
    const int rbase = blockIdx.x * 16;
    const int nbase = wave * 64;

    int rowa = rbase + m16; if (rowa >= M) rowa = M - 1;
    const unsigned short* xp = X + (size_t)rowa * 512 + q * 8;
    const unsigned short* w0 = Wt + (size_t)(nbase + m16) * 512 + q * 8;
    const unsigned short* w1 = w0 + 16 * 512;
    const unsigned short* w2 = w0 + 32 * 512;
    const unsigned short* w3 = w0 + 48 * 512;

    f32x4 ac0 = {0.f, 0.f, 0.f, 0.f}, ac1 = ac0, ac2 = ac0, ac3 = ac0;

#pragma unroll
    for (int k0 = 0; k0 < 512; k0 += 32) {
        bf16x8 a  = *(const bf16x8*)(xp + k0);
        bf16x8 b0 = *(const bf16x8*)(w0 + k0);
        bf16x8 b1 = *(const bf16x8*)(w1 + k0);
        bf16x8 b2 = *(const bf16x8*)(w2 + k0);
        bf16x8 b3 = *(const bf16x8*)(w3 + k0);
        ac0 = __builtin_amdgcn_mfma_f32_16x16x32_bf16(a, b0, ac0, 0, 0, 0);
        ac1 = __builtin_amdgcn_mfma_f32_16x16x32_bf16(a, b1, ac1, 0, 0, 0);
        ac2 = __builtin_amdgcn_mfma_f32_16x16x32_bf16(a, b2, ac2, 0, 0, 0);
        ac3 = __builtin_amdgcn_mfma_f32_16x16x32_bf16(a, b3, ac3, 0, 0, 0);
    }

#define EPI(AC, J) { \
        int coln = nbase + (J) * 16 + m16; \
        float bias = b[coln]; \
        _Pragma("unroll") \
        for (int r = 0; r < 4; ++r) { \
            int orow = rbase + q * 4 + r; \
            if (orow < M) \
                out[(size_t)orow * 256 + coln] = fmaxf(AC[r] + bias, 0.f); \
        } }
    EPI(ac0, 0) EPI(ac1, 1) EPI(ac2, 2) EPI(ac3, 3)
#undef EPI
}

// ---------------------------------------------------------------------------
extern "C" void kernel_launch(void* const* d_in, const int* in_sizes, int n_in,
                              void* d_out, int out_size, void* d_ws, size_t ws_size,
                              hipStream_t stream) {
    const float* x_gt   = (const float*)d_in[0];
    const float* x_ubs  = (const float*)d_in[1];
    const float* x_ag   = (const float*)d_in[2];
    const int* seen_src = (const int*)d_in[3];
    const int* seen_dst = (const int*)d_in[4];
    const int* near_src = (const int*)d_in[5];
    const int* near_dst = (const int*)d_in[6];
    const float* Ws_s = (const float*)d_in[7];  const float* bs_s = (const float*)d_in[8];
    const float* Wd_s = (const float*)d_in[9];  const float* bd_s = (const float*)d_in[10];
    const float* at_s = (const float*)d_in[11];
    const float* Wr_s = (const float*)d_in[12]; const float* br_s = (const float*)d_in[13];
    const float* Ws_n = (const float*)d_in[14]; const float* bs_n = (const float*)d_in[15];
    const float* Wd_n = (const float*)d_in[16]; const float* bd_n = (const float*)d_in[17];
    const float* at_n = (const float*)d_in[18];
    const float* Wr_n = (const float*)d_in[19]; const float* br_n = (const float*)d_in[20];
    const float* W_a  = (const float*)d_in[21]; const float* b_a  = (const float*)d_in[22];

    const int n_ag = in_sizes[2] / 16;
    const int E_s  = in_sizes[3];
    const int E_n  = in_sizes[5];

    char* ws = (char*)d_ws;
    int* cur_s = (int*)ws;              ws += (size_t)n_ag * 4;
    int* cur_n = (int*)ws;              ws += (size_t)n_ag * 4;
    int* csr_s = (int*)ws;              ws += (size_t)E_s * 4;
    int* csr_n = (int*)ws;              ws += (size_t)E_n * 4;
    unsigned short* xcat = (unsigned short*)ws;  ws += (size_t)n_ag * 512 * 2;
    unsigned short* Wt   = (unsigned short*)ws;  // [256][512] bf16

    hipMemsetAsync(cur_s, 0, (size_t)n_ag * 8, stream);  // cur_s, cur_n contiguous

    int gE = (E_s + E_n + 255) / 256;
    k_hist_wt<<<gE, 256, 0, stream>>>(seen_dst, E_s, near_dst, E_n, cur_s, cur_n, W_a, Wt);
    k_scan2<<<2, 1024, 0, stream>>>(cur_s, n_ag, cur_n, n_ag);
    k_scatter<<<gE, 256, 0, stream>>>(seen_src, seen_dst, E_s, near_src, near_dst, E_n,
                                      cur_s, cur_n, csr_s, csr_n);

    int gN = (n_ag + 15) / 16;   // 16 nodes per block (4 waves x 4 reps)
    k_gat<<<2 * gN, 256, 0, stream>>>(
        x_gt,  cur_s, csr_s, Ws_s, bs_s, Wd_s, bd_s, at_s, Wr_s, br_s,
        x_ubs, cur_n, csr_n, Ws_n, bs_n, Wd_n, bd_n, at_n, Wr_n, br_n,
        x_ag, xcat, n_ag, gN);

    k_mlp<<<(n_ag + 15) / 16, 256, 0, stream>>>(xcat, Wt, b_a, (float*)d_out, n_ag);
}

// Round 9
// 314.319 us; speedup vs baseline: 2.1257x; 1.1431x over previous
//
#include <hip/hip_runtime.h>
#include <math.h>

#define NEG 0.2f

typedef short bf16x8 __attribute__((ext_vector_type(8)));
typedef float f32x4  __attribute__((ext_vector_type(4)));

// ---------------------------------------------------------------------------
// helpers
// ---------------------------------------------------------------------------
static __device__ __forceinline__ void fma4(float4& d, float s, const float4 w) {
    d.x = fmaf(s, w.x, d.x); d.y = fmaf(s, w.y, d.y);
    d.z = fmaf(s, w.z, d.z); d.w = fmaf(s, w.w, d.w);
}
// leaky relu of (a+b): max(v, 0.2v) — valid since slope in (0,1)
static __device__ __forceinline__ float4 lrelu4(float4 a, float4 b) {
    float4 r; float v;
    v = a.x + b.x; r.x = fmaxf(v, NEG * v);
    v = a.y + b.y; r.y = fmaxf(v, NEG * v);
    v = a.z + b.z; r.z = fmaxf(v, NEG * v);
    v = a.w + b.w; r.w = fmaxf(v, NEG * v);
    return r;
}
static __device__ __forceinline__ unsigned short f2bf(float f) {   // RNE, finite
    unsigned int x = __float_as_uint(f);
    unsigned int r = (x + 0x7FFFu + ((x >> 16) & 1u)) >> 16;
    return (unsigned short)r;
}
static __device__ __forceinline__ float rlane(float v, int l) {
    return __int_as_float(__builtin_amdgcn_readlane(__float_as_int(v), l));
}

// Sum across each 16-lane DPP row (head h = lanes 16h..16h+15).
#define DPP_ADD(x, ctrl) \
    ((x) + __int_as_float(__builtin_amdgcn_update_dpp( \
        __float_as_int(x), __float_as_int(x), (ctrl), 0xF, 0xF, true)))
static __device__ __forceinline__ float rowsum16(float v) {
    v = DPP_ADD(v, 0xB1);   // quad_perm xor1
    v = DPP_ADD(v, 0x4E);   // quad_perm xor2
    v = DPP_ADD(v, 0x141);  // row_half_mirror
    v = DPP_ADD(v, 0x140);  // row_mirror
    return v;
}

// ---------------------------------------------------------------------------
// CSR build (separate dispatches; cooperative grid.sync measured ~120us per
// sync on 8 XCDs in R7). hist fused with W transpose.
// ---------------------------------------------------------------------------
__global__ void k_hist_wt(const int* __restrict__ dst_s, int Es,
                          const int* __restrict__ dst_n, int En,
                          int* __restrict__ deg_s, int* __restrict__ deg_n,
                          const float* __restrict__ W, unsigned short* __restrict__ Wt) {
    int i = blockIdx.x * 256 + threadIdx.x;
    if (i < Es) atomicAdd(&deg_s[dst_s[i]], 1);
    int j = i - Es;
    if (j >= 0 && j < En) atomicAdd(&deg_n[dst_n[j]], 1);
    if (i < 512 * 256) {                 // W[512][256] f32 -> Wt[256][512] bf16
        int k = i >> 8, n = i & 255;
        Wt[(size_t)n * 512 + k] = f2bf(W[i]);
    }
}

__global__ __launch_bounds__(1024) void k_scan2(int* a, int na, int* b, int nb) {
    int* p = (blockIdx.x == 0) ? a : b;
    int n  = (blockIdx.x == 0) ? na : nb;
    __shared__ int sums[1024];
    int t = threadIdx.x;
    int C = (n + 1023) >> 10;
    int base = t * C;
    int s = 0;
    for (int j = 0; j < C; ++j) { int i = base + j; if (i < n) s += p[i]; }
    sums[t] = s;
    __syncthreads();
    for (int off = 1; off < 1024; off <<= 1) {
        int v = (t >= off) ? sums[t - off] : 0;
        __syncthreads();
        sums[t] += v;
        __syncthreads();
    }
    int run = (t == 0) ? 0 : sums[t - 1];
    for (int j = 0; j < C; ++j) {
        int i = base + j;
        if (i < n) { int v = p[i]; p[i] = run; run += v; }
    }
}

__global__ void k_scatter(const int* __restrict__ src_s, const int* __restrict__ dst_s, int Es,
                          const int* __restrict__ src_n, const int* __restrict__ dst_n, int En,
                          int* __restrict__ cur_s, int* __restrict__ cur_n,
                          int* __restrict__ csr_s, int* __restrict__ csr_n) {
    int i = blockIdx.x * 256 + threadIdx.x;
    if (i < Es) {
        int pos = atomicAdd(&cur_s[dst_s[i]], 1);
        csr_s[pos] = src_s[i];
    }
    int j = i - Es;
    if (j >= 0 && j < En) {
        int pos = atomicAdd(&cur_n[dst_n[j]], 1);
        csr_n[pos] = src_n[j];
    }
}

// ---------------------------------------------------------------------------
// GATv2, both layers fused by contiguous block ranges (block < gNs -> seen).
// Four nodes per wave (16/block). NEW in R9: fd/fr for all 4 nodes computed
// in ONE streaming pass over the 32 Wd/Wr rows -- one scatter load gathers
// the 4 agent rows into the wave's lanes (lane L = feat L&15 of node L>>4),
// each weight-row load feeds 4 readlane FMAs (independent loads, 16 FMA
// per load -> latency hidden). R8 re-ran a dependent 32-load chain per node
// (L1 thrashed by the gather stream -> ~1.5K stall-cyc per node).
// Edge loop: lanes-as-row-buffer, 1-VGPR double buffer (no-spill, R6).
// No online max (|score| bounded -> exp safe). pfx bounds prefetched.
// ---------------------------------------------------------------------------
__global__ __launch_bounds__(256) void k_gat(
    const float* __restrict__ xsrc_s, const int* __restrict__ pfx_s, const int* __restrict__ csr_s,
    const float* __restrict__ Ws_s, const float* __restrict__ bs_s,
    const float* __restrict__ Wd_s, const float* __restrict__ bd_s,
    const float* __restrict__ at_s,
    const float* __restrict__ Wr_s, const float* __restrict__ br_s,
    const float* __restrict__ xsrc_n, const int* __restrict__ pfx_n, const int* __restrict__ csr_n,
    const float* __restrict__ Ws_n, const float* __restrict__ bs_n,
    const float* __restrict__ Wd_n, const float* __restrict__ bd_n,
    const float* __restrict__ at_n,
    const float* __restrict__ Wr_n, const float* __restrict__ br_n,
    const float* __restrict__ x_ag,
    unsigned short* __restrict__ xcat, int n_dst, int gNs)
{
    const bool seen = (int)blockIdx.x < gNs;
    const float* x_src = seen ? xsrc_s : xsrc_n;
    const int*   pfx   = seen ? pfx_s  : pfx_n;
    const int*   csr   = seen ? csr_s  : csr_n;
    const float* Ws    = seen ? Ws_s   : Ws_n;
    const float* bs    = seen ? bs_s   : bs_n;
    const float* Wd    = seen ? Wd_s   : Wd_n;
    const float* bd    = seen ? bd_s   : bd_n;
    const float* at    = seen ? at_s   : at_n;
    const float* Wr    = seen ? Wr_s   : Wr_n;
    const float* br    = seen ? br_s   : br_n;
    const int col = seen ? 0 : 256;
    const int blk = seen ? (int)blockIdx.x : (int)blockIdx.x - gNs;

    const int t = threadIdx.x;
    const int wave = t >> 6, lane = t & 63;
    const int d0 = lane * 4;

    // ---- gather the wave's 4 agent rows: lane L = feat (L&15) of node L>>4
    int gnode = blk * 16 + ((lane >> 4) << 2) + wave;
    int gn = (gnode < n_dst) ? gnode : (n_dst - 1);
    float xag = x_ag[(size_t)gn * 16 + (lane & 15)];

    // ---- prefetch the 4 nodes' edge ranges (overlaps fd/fr pass)
    int e_start[4], e_end[4];
#pragma unroll
    for (int j = 0; j < 4; ++j) {
        int nd = blk * 16 + j * 4 + wave;
        nd = (nd < n_dst) ? nd : (n_dst - 1);
        e_end[j]   = pfx[nd];
        e_start[j] = nd ? pfx[nd - 1] : 0;
    }

    // ---- fd/fr for all 4 nodes in ONE pass over the 32 weight rows
    float4 fd4[4], fr4[4];
    {
        const float4 bdv = *(const float4*)&bd[d0];
        const float4 brv = *(const float4*)&br[d0];
#pragma unroll
        for (int j = 0; j < 4; ++j) { fd4[j] = bdv; fr4[j] = brv; }
#pragma unroll
        for (int k = 0; k < 16; ++k) {
            float4 wd = *(const float4*)&Wd[k * 256 + d0];
            float4 wr = *(const float4*)&Wr[k * 256 + d0];
#pragma unroll
            for (int j = 0; j < 4; ++j) {
                float xk = rlane(xag, j * 16 + k);
                fma4(fd4[j], xk, wd);
                fma4(fr4[j], xk, wr);
            }
        }
    }

    // ---- wave-lifetime edge-loop constants
    float4 ws_r[8];
#pragma unroll
    for (int k = 0; k < 8; ++k) ws_r[k] = *(const float4*)&Ws[k * 256 + d0];
    const float4 bsv = *(const float4*)&bs[d0];
    const float4 atv = *(const float4*)&at[d0];

#pragma unroll
    for (int rep = 0; rep < 4; ++rep) {
        const int node = blk * 16 + rep * 4 + wave;
        if (node >= n_dst) continue;

        const int start = e_start[rep];
        const int deg   = e_end[rep] - start;
        const float4 fd = fd4[rep];
        const float4 fr = fr4[rep];

        float l = 0.f;
        float4 acc = make_float4(0.f, 0.f, 0.f, 0.f);

        if (deg > 0) {
            const int g  = lane >> 3;   // edge slot 0..7 within chunk
            const int w8 = lane & 7;    // word within the 8-float row

            int e0 = (g < deg) ? g : deg - 1;
            int i0 = csr[start + e0];
            float r0 = x_src[(size_t)i0 * 8 + w8];        // 8 rows in flight
            int e1 = (8 + g < deg) ? 8 + g : deg - 1;
            int i1 = csr[start + e1];

            for (int base = 0; base < deg; base += 8) {
                float r1 = x_src[(size_t)i1 * 8 + w8];
                int e2 = base + 16 + g; e2 = (e2 < deg) ? e2 : deg - 1;
                int i2 = csr[start + e2];

#pragma unroll
                for (int j = 0; j < 8; ++j) {
                    if (base + j < deg) {      // wave-uniform -> scalar branch
                        float x0 = rlane(r0, j * 8 + 0);
                        float x1 = rlane(r0, j * 8 + 1);
                        float x2 = rlane(r0, j * 8 + 2);
                        float x3 = rlane(r0, j * 8 + 3);
                        float x4 = rlane(r0, j * 8 + 4);
                        float x5 = rlane(r0, j * 8 + 5);
                        float x6 = rlane(r0, j * 8 + 6);
                        float x7 = rlane(r0, j * 8 + 7);

                        float4 fs = bsv;
                        fma4(fs, x0, ws_r[0]);
                        fma4(fs, x1, ws_r[1]);
                        fma4(fs, x2, ws_r[2]);
                        fma4(fs, x3, ws_r[3]);
                        fma4(fs, x4, ws_r[4]);
                        fma4(fs, x5, ws_r[5]);
                        fma4(fs, x6, ws_r[6]);
                        fma4(fs, x7, ws_r[7]);

                        float4 tt = lrelu4(fs, fd);
                        float sc = tt.x * atv.x;
                        sc = fmaf(tt.y, atv.y, sc);
                        sc = fmaf(tt.z, atv.z, sc);
                        sc = fmaf(tt.w, atv.w, sc);
                        sc = rowsum16(sc);

                        float p = __expf(sc);   // no max shift: |sc| bounded
                        l += p;
                        acc.x = fmaf(p, fs.x, acc.x);
                        acc.y = fmaf(p, fs.y, acc.y);
                        acc.z = fmaf(p, fs.z, acc.z);
                        acc.w = fmaf(p, fs.w, acc.w);
                    }
                }
                r0 = r1; i1 = i2;
            }
        }

        float inv = (l > 0.f) ? 1.f / l : 0.f;   // zero in-degree -> rst = 0
        ushort4 o;
        o.x = f2bf(fmaxf(fmaf(acc.x, inv, fr.x), 0.f));
        o.y = f2bf(fmaxf(fmaf(acc.y, inv, fr.y), 0.f));
        o.z = f2bf(fmaxf(fmaf(acc.z, inv, fr.z), 0.f));
        o.w = f2bf(fmaxf(fmaf(acc.w, inv, fr.w), 0.f));
        *(ushort4*)&xcat[(size_t)node * 512 + col + d0] = o;
    }
}

// ---------------------------------------------------------------------------
// out = relu(X[M,512]bf16 @ W[512,256]bf16 + b) via mfma_f32_16x16x32_bf16.
// Block = 4 waves: rows rbase..rbase+15, wave w covers cols 64w..64w+63.
// A/B frags straight from L2 (no LDS). D: col n=lane&15, row m=q*4+reg.
// ---------------------------------------------------------------------------
__global__ __launch_bounds__(256) void k_mlp(
    const unsigned short* __restrict__ X, const unsigned short* __restrict__ Wt,
    const float* __restrict__ b, float* __restrict__ out, int M)
{
    const int t = threadIdx.x;
    const int wave = t >> 6, lane = t & 63;
    const int m16 = lane & 15, q = lane >> 4;
    const int rbase = blockIdx.x * 16;
    const int nbase = wave * 64;

    int rowa = rbase + m16; if (rowa >= M) rowa = M - 1;
    const unsigned short* xp = X + (size_t)rowa * 512 + q * 8;
    const unsigned short* w0 = Wt + (size_t)(nbase + m16) * 512 + q * 8;
    const unsigned short* w1 = w0 + 16 * 512;
    const unsigned short* w2 = w0 + 32 * 512;
    const unsigned short* w3 = w0 + 48 * 512;

    f32x4 ac0 = {0.f, 0.f, 0.f, 0.f}, ac1 = ac0, ac2 = ac0, ac3 = ac0;

#pragma unroll
    for (int k0 = 0; k0 < 512; k0 += 32) {
        bf16x8 a  = *(const bf16x8*)(xp + k0);
        bf16x8 b0 = *(const bf16x8*)(w0 + k0);
        bf16x8 b1 = *(const bf16x8*)(w1 + k0);
        bf16x8 b2 = *(const bf16x8*)(w2 + k0);
        bf16x8 b3 = *(const bf16x8*)(w3 + k0);
        ac0 = __builtin_amdgcn_mfma_f32_16x16x32_bf16(a, b0, ac0, 0, 0, 0);
        ac1 = __builtin_amdgcn_mfma_f32_16x16x32_bf16(a, b1, ac1, 0, 0, 0);
        ac2 = __builtin_amdgcn_mfma_f32_16x16x32_bf16(a, b2, ac2, 0, 0, 0);
        ac3 = __builtin_amdgcn_mfma_f32_16x16x32_bf16(a, b3, ac3, 0, 0, 0);
    }

#define EPI(AC, J) { \
        int coln = nbase + (J) * 16 + m16; \
        float bias = b[coln]; \
        _Pragma("unroll") \
        for (int r = 0; r < 4; ++r) { \
            int orow = rbase + q * 4 + r; \
            if (orow < M) \
                out[(size_t)orow * 256 + coln] = fmaxf(AC[r] + bias, 0.f); \
        } }
    EPI(ac0, 0) EPI(ac1, 1) EPI(ac2, 2) EPI(ac3, 3)
#undef EPI
}

// ---------------------------------------------------------------------------
extern "C" void kernel_launch(void* const* d_in, const int* in_sizes, int n_in,
                              void* d_out, int out_size, void* d_ws, size_t ws_size,
                              hipStream_t stream) {
    const float* x_gt   = (const float*)d_in[0];
    const float* x_ubs  = (const float*)d_in[1];
    const float* x_ag   = (const float*)d_in[2];
    const int* seen_src = (const int*)d_in[3];
    const int* seen_dst = (const int*)d_in[4];
    const int* near_src = (const int*)d_in[5];
    const int* near_dst = (const int*)d_in[6];
    const float* Ws_s = (const float*)d_in[7];  const float* bs_s = (const float*)d_in[8];
    const float* Wd_s = (const float*)d_in[9];  const float* bd_s = (const float*)d_in[10];
    const float* at_s = (const float*)d_in[11];
    const float* Wr_s = (const float*)d_in[12]; const float* br_s = (const float*)d_in[13];
    const float* Ws_n = (const float*)d_in[14]; const float* bs_n = (const float*)d_in[15];
    const float* Wd_n = (const float*)d_in[16]; const float* bd_n = (const float*)d_in[17];
    const float* at_n = (const float*)d_in[18];
    const float* Wr_n = (const float*)d_in[19]; const float* br_n = (const float*)d_in[20];
    const float* W_a  = (const float*)d_in[21]; const float* b_a  = (const float*)d_in[22];

    const int n_ag = in_sizes[2] / 16;
    const int E_s  = in_sizes[3];
    const int E_n  = in_sizes[5];

    char* ws = (char*)d_ws;
    int* cur_s = (int*)ws;              ws += (size_t)n_ag * 4;
    int* cur_n = (int*)ws;              ws += (size_t)n_ag * 4;
    int* csr_s = (int*)ws;              ws += (size_t)E_s * 4;
    int* csr_n = (int*)ws;              ws += (size_t)E_n * 4;
    unsigned short* xcat = (unsigned short*)ws;  ws += (size_t)n_ag * 512 * 2;
    unsigned short* Wt   = (unsigned short*)ws;  // [256][512] bf16

    hipMemsetAsync(cur_s, 0, (size_t)n_ag * 8, stream);  // cur_s, cur_n contiguous

    int gE = (E_s + E_n + 255) / 256;
    k_hist_wt<<<gE, 256, 0, stream>>>(seen_dst, E_s, near_dst, E_n, cur_s, cur_n, W_a, Wt);
    k_scan2<<<2, 1024, 0, stream>>>(cur_s, n_ag, cur_n, n_ag);
    k_scatter<<<gE, 256, 0, stream>>>(seen_src, seen_dst, E_s, near_src, near_dst, E_n,
                                      cur_s, cur_n, csr_s, csr_n);

    int gN = (n_ag + 15) / 16;   // 16 nodes per block (4 waves x 4 reps)
    k_gat<<<2 * gN, 256, 0, stream>>>(
        x_gt,  cur_s, csr_s, Ws_s, bs_s, Wd_s, bd_s, at_s, Wr_s, br_s,
        x_ubs, cur_n, csr_n, Ws_n, bs_n, Wd_n, bd_n, at_n, Wr_n, br_n,
        x_ag, xcat, n_ag, gN);

    k_mlp<<<(n_ag + 15) / 16, 256, 0, stream>>>(xcat, Wt, b_a, (float*)d_out, n_ag);
}